// Round 10
// baseline (148.534 us; speedup 1.0000x reference)
//
#include <hip/hip_runtime.h>
#include <math.h>

// MelGaussianFilteredMSE:
//   diff = 10^(mo/10) - 10^(tg/10)            (B=32, F=1025, T=2000, fp32)
//   out  = mean( (M @ diff along F)^2 )       M is BANDED: half-width <= 10
//
// R9 = R8 skeleton (NOUT=106, CT=512, NT=256, lb(256,4), PF=3 ring, s_load
// coeffs, FETCH=315MB preserved) + PACKED FP32 FIR:
//   - band stores duplicated coefficient pairs (c,c); per-tap one
//     v_pk_fma_f32 (VOP3P): dst/addend = float2 accum (VGPR pair),
//     src0 = coeff pair from SGPRs (the one allowed scalar operand),
//     src1 = float2 window slot. FIR: 42 scalar FMA -> 21 pk FMA.
//   - two 11-deep partial chains to halve dependency latency.

#define B_N 32
#define F_N 1025
#define T_N 2000

#define NOUT   106   // output rows per f-chunk; streamed rows = 126 = 6*21
#define NCHUNK 10
#define NT     256   // threads per block
#define CT     512   // t-columns per block (256 threads * 2)
#define PF     3     // ring depth; 21 % 3 == 0 -> static slots
#define CBS2   48    // band row stride in floats (21 dup pairs + pad, 192 B)
#define BANDROWS (NCHUNK * NOUT)     // 1060 rows; rows >= 1025 all-zero

#define K_E 0.33219280948873623f     // log2(10)/10 : 10^(x/10) = 2^(x*K_E)

typedef float v2f __attribute__((ext_vector_type(2)));

__global__ void build_band(const float* __restrict__ M, float* __restrict__ band) {
    const int idx = blockIdx.x * 256 + threadIdx.x;
    if (idx >= BANDROWS * CBS2) return;
    const int f  = idx / CBS2;
    const int j2 = idx - f * CBS2;
    const int j  = j2 >> 1;                    // tap index (duplicated pair)
    const int k  = f - 10 + j;
    float v = 0.f;
    if (j < 21 && f < F_N && k >= 0 && k < F_N) v = M[(size_t)f * F_N + k];
    band[idx] = v;
}

__global__ __launch_bounds__(NT, 4)
void mel_mse_stream(const float* __restrict__ mo_g, const float* __restrict__ tg_g,
                    const float* __restrict__ band, float* __restrict__ partials) {
    __shared__ float red[NT];

    const int tid = threadIdx.x;
    const int t0  = blockIdx.x * CT;
    const int f0  = blockIdx.y * NOUT;   // uniform
    const int b   = blockIdx.z;          // uniform
    const int t   = t0 + tid * 2;
    const bool colv = (t + 1 < T_N);     // T_N even: pair fully valid or not
    const int  tc   = colv ? t : 0;
    const int  base = f0 - 10;

    const size_t colbase = ((size_t)b * F_N) * (size_t)T_N + tc;

    v2f    w[21];                        // diff window (static-indexed)
    float2 ra[PF], rc[PF];               // raw prefetch rings
    v2f    acc2 = {0.f, 0.f};

    // issue stream row n into ring slot s; row math is scalar/uniform
    auto ISSUE = [&](int n, int s) {
        int g = base + n;
        g = g < 0 ? 0 : (g > F_N - 1 ? F_N - 1 : g);   // OOB -> coeff is 0
        const size_t off = colbase + (size_t)g * T_N;
        ra[s] = *reinterpret_cast<const float2*>(mo_g + off);
        rc[s] = *reinterpret_cast<const float2*>(tg_g + off);
    };
    auto CONS = [&](int s, int ws) {
        const float2 a = ra[s], c = rc[s];
        w[ws].x = exp2f(a.x * K_E) - exp2f(c.x * K_E);
        w[ws].y = exp2f(a.y * K_E) - exp2f(c.y * K_E);
    };
    // emit global output row frow; s0 = window slot of tap 0 (compile-time).
    // Coeff pairs are uniform -> SGPR pairs; v_pk_fma reads them as the one
    // allowed scalar operand of a VOP3P instruction.
    auto OUT = [&](int frow, int s0) {
        const v2f* crow = reinterpret_cast<const v2f*>(band + (size_t)frow * CBS2);
        v2f oa = {0.f, 0.f}, ob = {0.f, 0.f};
#pragma unroll
        for (int j = 0; j < 21; j += 2) {
            const v2f c2 = crow[j];
            const v2f w2 = w[(s0 + j) % 21];
            asm("v_pk_fma_f32 %0, %1, %2, %0" : "+v"(oa) : "s"(c2), "v"(w2));
        }
#pragma unroll
        for (int j = 1; j < 21; j += 2) {
            const v2f c2 = crow[j];
            const v2f w2 = w[(s0 + j) % 21];
            asm("v_pk_fma_f32 %0, %1, %2, %0" : "+v"(ob) : "s"(c2), "v"(w2));
        }
        const v2f o2 = oa + ob;
        asm("v_pk_fma_f32 %0, %1, %1, %0" : "+v"(acc2) : "v"(o2));
    };

    // ---- prologue: rows 0..2 in flight ----
#pragma unroll
    for (int i = 0; i < PF; ++i) ISSUE(i, i);

    // ---- macro 0 (rows 0..20): fill window; first output at i==20 ----
#pragma unroll
    for (int i = 0; i < 21; ++i) {
        CONS(i % PF, i);
        ISSUE(i + PF, i % PF);                    // rows 3..23
        if (i == 20) OUT(f0, 0);
    }
    // ---- macros 1..5 (rows 21..125): one output per row ----
    for (int m = 1; m < 6; ++m) {
        const int nb = m * 21;
#pragma unroll
        for (int i = 0; i < 21; ++i) {
            CONS(i % PF, i);
            ISSUE(nb + i + PF, i % PF);
            OUT(f0 + nb + i - 20, (i + 1) % 21);  // static slot base
        }
    }

    // ---- block reduction ----
    red[tid] = colv ? (acc2.x + acc2.y) : 0.f;
    __syncthreads();
    for (int s = NT / 2; s > 0; s >>= 1) {
        if (tid < s) red[tid] += red[tid + s];
        __syncthreads();
    }
    if (tid == 0) {
        const int bid = blockIdx.x + gridDim.x * (blockIdx.y + gridDim.y * blockIdx.z);
        partials[bid] = red[0];
    }
}

__global__ void mel_mse_reduce(const float* __restrict__ partials, int n,
                               float* __restrict__ out) {
    __shared__ double red[256];
    double s = 0.0;
    for (int i = threadIdx.x; i < n; i += 256) s += (double)partials[i];
    red[threadIdx.x] = s;
    __syncthreads();
    for (int st = 128; st > 0; st >>= 1) {
        if (threadIdx.x < st) red[threadIdx.x] += red[threadIdx.x + st];
        __syncthreads();
    }
    if (threadIdx.x == 0)
        out[0] = (float)(red[0] / (double)((long long)B_N * F_N * T_N));
}

extern "C" void kernel_launch(void* const* d_in, const int* in_sizes, int n_in,
                              void* d_out, int out_size, void* d_ws, size_t ws_size,
                              hipStream_t stream) {
    const float* mo = (const float*)d_in[0];   // model_output (32,1025,2000) fp32
    const float* tg = (const float*)d_in[1];   // target       (32,1025,2000) fp32
    const float* M  = (const float*)d_in[2];   // transform_matrix (1025,1025) fp32
    float* out      = (float*)d_out;

    float* band     = (float*)d_ws;                      // 1060*48*4 = 203520 B
    float* partials = (float*)((char*)d_ws + 204800);    // 1280*4    =   5120 B

    build_band<<<(BANDROWS * CBS2 + 255) / 256, 256, 0, stream>>>(M, band);

    dim3 grid((T_N + CT - 1) / CT,             // 4 t-tiles
              NCHUNK,                          // 10 f-chunks
              B_N);                            // 32 batches -> 1280 blocks
    const int nparts = grid.x * grid.y * grid.z;

    mel_mse_stream<<<grid, NT, 0, stream>>>(mo, tg, band, partials);
    mel_mse_reduce<<<1, 256, 0, stream>>>(partials, nparts, out);
}

// Round 11
// 134.222 us; speedup vs baseline: 1.1066x; 1.1066x over previous
//
#include <hip/hip_runtime.h>
#include <math.h>

// MelGaussianFilteredMSE:
//   diff = 10^(mo/10) - 10^(tg/10)            (B=32, F=1025, T=2000, fp32)
//   out  = mean( (M @ diff along F)^2 )       M is BANDED: half-width <= 10
//
// R10 = R8 (best: 124.6 us; NOUT=106, PF=3 ring, s_load coeffs, FETCH=315MB)
// with two deltas:
//  - revert R9's v_pk_fma asm (it regressed: schedule perturbation > issue win)
//  - CT 512->256: one scalar float column per thread -> grid 2560 blocks =
//    10 blocks/CU. Occupancy was GRID-capped at 5 blocks/CU x 4 waves (62.5%
//    max, 43-54% measured) in every prior round; wave supply now 40/CU,
//    HW-capped at 32. lb(256,8); ~50 VGPRs fits 8 waves/SIMD.

#define B_N 32
#define F_N 1025
#define T_N 2000

#define NOUT   106   // output rows per f-chunk; streamed rows = 126 = 6*21
#define NCHUNK 10
#define NT     256   // threads per block
#define CT     256   // t-columns per block (1 float col per thread)
#define PF     3     // ring depth; 21 % 3 == 0 -> static slots
#define CBS    24    // band row stride in floats (96 B, float4-aligned)
#define BANDROWS (NCHUNK * NOUT)     // 1060 rows; rows >= 1025 all-zero

#define K_E 0.33219280948873623f     // log2(10)/10 : 10^(x/10) = 2^(x*K_E)

__global__ void build_band(const float* __restrict__ M, float* __restrict__ band) {
    const int idx = blockIdx.x * 256 + threadIdx.x;
    if (idx >= BANDROWS * CBS) return;
    const int f = idx / CBS;
    const int j = idx - f * CBS;
    const int k = f - 10 + j;
    float v = 0.f;
    if (j < 21 && f < F_N && k >= 0 && k < F_N) v = M[(size_t)f * F_N + k];
    band[idx] = v;
}

__global__ __launch_bounds__(NT, 8)
void mel_mse_stream(const float* __restrict__ mo_g, const float* __restrict__ tg_g,
                    const float* __restrict__ band, float* __restrict__ partials) {
    __shared__ float red[NT];

    const int tid = threadIdx.x;
    const int t0  = blockIdx.x * CT;
    const int f0  = blockIdx.y * NOUT;   // uniform
    const int b   = blockIdx.z;          // uniform
    const int t   = t0 + tid;
    const bool colv = (t < T_N);
    const int  tc   = colv ? t : 0;
    const int  base = f0 - 10;

    const size_t colbase = ((size_t)b * F_N) * (size_t)T_N + tc;

    float w[21];                         // diff window (static-indexed)
    float ra[PF], rc[PF];                // raw prefetch rings
    float acc = 0.f;

    // issue stream row n into ring slot s; row math is scalar/uniform
    auto ISSUE = [&](int n, int s) {
        int g = base + n;
        g = g < 0 ? 0 : (g > F_N - 1 ? F_N - 1 : g);   // OOB -> coeff is 0
        const size_t off = colbase + (size_t)g * T_N;
        ra[s] = mo_g[off];
        rc[s] = tg_g[off];
    };
    auto CONS = [&](int s, int ws) {
        w[ws] = exp2f(ra[s] * K_E) - exp2f(rc[s] * K_E);
    };
    // emit global output row frow; s0 = window slot of tap 0 (compile-time).
    // Coeff address is uniform -> s_load into SGPRs; FMA reads s-operand.
    auto OUT = [&](int frow, int s0) {
        const float4* c4 = reinterpret_cast<const float4*>(band + (size_t)frow * CBS);
        float cf[24];
#pragma unroll
        for (int q = 0; q < 6; ++q)
            *reinterpret_cast<float4*>(&cf[4 * q]) = c4[q];
        float o = 0.f;
#pragma unroll
        for (int j = 0; j < 21; ++j)
            o = fmaf(cf[j], w[(s0 + j) % 21], o);
        acc = fmaf(o, o, acc);
    };

    // ---- prologue: rows 0..2 in flight ----
#pragma unroll
    for (int i = 0; i < PF; ++i) ISSUE(i, i);

    // ---- macro 0 (rows 0..20): fill window; first output at i==20 ----
#pragma unroll
    for (int i = 0; i < 21; ++i) {
        CONS(i % PF, i);
        ISSUE(i + PF, i % PF);                    // rows 3..23
        if (i == 20) OUT(f0, 0);
    }
    // ---- macros 1..5 (rows 21..125): one output per row ----
    for (int m = 1; m < 6; ++m) {
        const int nb = m * 21;
#pragma unroll
        for (int i = 0; i < 21; ++i) {
            CONS(i % PF, i);
            ISSUE(nb + i + PF, i % PF);
            OUT(f0 + nb + i - 20, (i + 1) % 21);  // static slot base
        }
    }

    // ---- block reduction ----
    red[tid] = colv ? acc : 0.f;
    __syncthreads();
    for (int s = NT / 2; s > 0; s >>= 1) {
        if (tid < s) red[tid] += red[tid + s];
        __syncthreads();
    }
    if (tid == 0) {
        const int bid = blockIdx.x + gridDim.x * (blockIdx.y + gridDim.y * blockIdx.z);
        partials[bid] = red[0];
    }
}

__global__ void mel_mse_reduce(const float* __restrict__ partials, int n,
                               float* __restrict__ out) {
    __shared__ double red[256];
    double s = 0.0;
    for (int i = threadIdx.x; i < n; i += 256) s += (double)partials[i];
    red[threadIdx.x] = s;
    __syncthreads();
    for (int st = 128; st > 0; st >>= 1) {
        if (threadIdx.x < st) red[threadIdx.x] += red[threadIdx.x + st];
        __syncthreads();
    }
    if (threadIdx.x == 0)
        out[0] = (float)(red[0] / (double)((long long)B_N * F_N * T_N));
}

extern "C" void kernel_launch(void* const* d_in, const int* in_sizes, int n_in,
                              void* d_out, int out_size, void* d_ws, size_t ws_size,
                              hipStream_t stream) {
    const float* mo = (const float*)d_in[0];   // model_output (32,1025,2000) fp32
    const float* tg = (const float*)d_in[1];   // target       (32,1025,2000) fp32
    const float* M  = (const float*)d_in[2];   // transform_matrix (1025,1025) fp32
    float* out      = (float*)d_out;

    float* band     = (float*)d_ws;                      // 1060*24*4 = 101760 B
    float* partials = (float*)((char*)d_ws + 102400);    // 2560*4    =  10240 B

    build_band<<<(BANDROWS * CBS + 255) / 256, 256, 0, stream>>>(M, band);

    dim3 grid((T_N + CT - 1) / CT,             // 8 t-tiles
              NCHUNK,                          // 10 f-chunks
              B_N);                            // 32 batches -> 2560 blocks
    const int nparts = grid.x * grid.y * grid.z;

    mel_mse_stream<<<grid, NT, 0, stream>>>(mo, tg, band, partials);
    mel_mse_reduce<<<1, 256, 0, stream>>>(partials, nparts, out);
}

// Round 12
// 126.740 us; speedup vs baseline: 1.1720x; 1.0590x over previous
//
#include <hip/hip_runtime.h>
#include <math.h>

// MelGaussianFilteredMSE:
//   diff = 10^(mo/10) - 10^(tg/10)            (B=32, F=1025, T=2000, fp32)
//   out  = mean( (M @ diff along F)^2 )       M is BANDED: half-width <= 10
//
// R11 = R8 (best: 124.6 us; NOUT=106, CT=512 float2, NT=256, lb(256,4),
// s_load coeffs from pre-packed band, FETCH=315MB) with ONE delta:
//   prefetch ring depth PF 3 -> 7 (14 loads in flight per wave, 3.5 KB).
// Tests whether effective memory concurrency per wave is the binding
// constraint behind the ~2.5 TB/s effective HBM rate. 21 % 7 == 0 keeps
// all ring slots compile-time static.

#define B_N 32
#define F_N 1025
#define T_N 2000

#define NOUT   106   // output rows per f-chunk; streamed rows = 126 = 6*21
#define NCHUNK 10
#define NT     256   // threads per block
#define CT     512   // t-columns per block (256 threads * 2)
#define PF     7     // ring depth; 21 % 7 == 0 -> static slots
#define CBS    24    // band row stride in floats (96 B, float4-aligned)
#define BANDROWS (NCHUNK * NOUT)     // 1060 rows; rows >= 1025 all-zero

#define K_E 0.33219280948873623f     // log2(10)/10 : 10^(x/10) = 2^(x*K_E)

__global__ void build_band(const float* __restrict__ M, float* __restrict__ band) {
    const int idx = blockIdx.x * 256 + threadIdx.x;
    if (idx >= BANDROWS * CBS) return;
    const int f = idx / CBS;
    const int j = idx - f * CBS;
    const int k = f - 10 + j;
    float v = 0.f;
    if (j < 21 && f < F_N && k >= 0 && k < F_N) v = M[(size_t)f * F_N + k];
    band[idx] = v;
}

__global__ __launch_bounds__(NT, 4)
void mel_mse_stream(const float* __restrict__ mo_g, const float* __restrict__ tg_g,
                    const float* __restrict__ band, float* __restrict__ partials) {
    __shared__ float red[NT];

    const int tid = threadIdx.x;
    const int t0  = blockIdx.x * CT;
    const int f0  = blockIdx.y * NOUT;   // uniform
    const int b   = blockIdx.z;          // uniform
    const int t   = t0 + tid * 2;
    const bool colv = (t + 1 < T_N);     // T_N even: pair fully valid or not
    const int  tc   = colv ? t : 0;
    const int  base = f0 - 10;

    const size_t colbase = ((size_t)b * F_N) * (size_t)T_N + tc;

    float2 w[21];                        // diff window (static-indexed)
    float2 ra[PF], rc[PF];               // raw prefetch rings (14 loads in flight)
    float  acc = 0.f;

    // issue stream row n into ring slot s; row math is scalar/uniform
    auto ISSUE = [&](int n, int s) {
        int g = base + n;
        g = g < 0 ? 0 : (g > F_N - 1 ? F_N - 1 : g);   // OOB -> coeff is 0
        const size_t off = colbase + (size_t)g * T_N;
        ra[s] = *reinterpret_cast<const float2*>(mo_g + off);
        rc[s] = *reinterpret_cast<const float2*>(tg_g + off);
    };
    auto CONS = [&](int s, int ws) {
        const float2 a = ra[s], c = rc[s];
        w[ws].x = exp2f(a.x * K_E) - exp2f(c.x * K_E);
        w[ws].y = exp2f(a.y * K_E) - exp2f(c.y * K_E);
    };
    // emit global output row frow; s0 = window slot of tap 0 (compile-time).
    // Coeff address is uniform -> s_load into SGPRs; FMA reads s-operand.
    auto OUT = [&](int frow, int s0) {
        const float4* c4 = reinterpret_cast<const float4*>(band + (size_t)frow * CBS);
        float cf[24];
#pragma unroll
        for (int q = 0; q < 6; ++q)
            *reinterpret_cast<float4*>(&cf[4 * q]) = c4[q];
        float2 o = make_float2(0.f, 0.f);
#pragma unroll
        for (int j = 0; j < 21; ++j) {
            const float2 wv = w[(s0 + j) % 21];
            o.x = fmaf(cf[j], wv.x, o.x);
            o.y = fmaf(cf[j], wv.y, o.y);
        }
        acc = fmaf(o.x, o.x, fmaf(o.y, o.y, acc));
    };

    // ---- prologue: rows 0..6 in flight ----
#pragma unroll
    for (int i = 0; i < PF; ++i) ISSUE(i, i);

    // ---- macro 0 (rows 0..20): fill window; first output at i==20 ----
#pragma unroll
    for (int i = 0; i < 21; ++i) {
        CONS(i % PF, i);
        ISSUE(i + PF, i % PF);                    // rows 7..27
        if (i == 20) OUT(f0, 0);
    }
    // ---- macros 1..5 (rows 21..125): one output per row ----
    // (trailing over-issues are clamped-address loads, values unused)
    for (int m = 1; m < 6; ++m) {
        const int nb = m * 21;                    // 21 % PF == 0 -> slot = i % PF
#pragma unroll
        for (int i = 0; i < 21; ++i) {
            CONS(i % PF, i);
            ISSUE(nb + i + PF, i % PF);
            OUT(f0 + nb + i - 20, (i + 1) % 21);  // static slot base
        }
    }

    // ---- block reduction ----
    red[tid] = colv ? acc : 0.f;
    __syncthreads();
    for (int s = NT / 2; s > 0; s >>= 1) {
        if (tid < s) red[tid] += red[tid + s];
        __syncthreads();
    }
    if (tid == 0) {
        const int bid = blockIdx.x + gridDim.x * (blockIdx.y + gridDim.y * blockIdx.z);
        partials[bid] = red[0];
    }
}

__global__ void mel_mse_reduce(const float* __restrict__ partials, int n,
                               float* __restrict__ out) {
    __shared__ double red[256];
    double s = 0.0;
    for (int i = threadIdx.x; i < n; i += 256) s += (double)partials[i];
    red[threadIdx.x] = s;
    __syncthreads();
    for (int st = 128; st > 0; st >>= 1) {
        if (threadIdx.x < st) red[threadIdx.x] += red[threadIdx.x + st];
        __syncthreads();
    }
    if (threadIdx.x == 0)
        out[0] = (float)(red[0] / (double)((long long)B_N * F_N * T_N));
}

extern "C" void kernel_launch(void* const* d_in, const int* in_sizes, int n_in,
                              void* d_out, int out_size, void* d_ws, size_t ws_size,
                              hipStream_t stream) {
    const float* mo = (const float*)d_in[0];   // model_output (32,1025,2000) fp32
    const float* tg = (const float*)d_in[1];   // target       (32,1025,2000) fp32
    const float* M  = (const float*)d_in[2];   // transform_matrix (1025,1025) fp32
    float* out      = (float*)d_out;

    float* band     = (float*)d_ws;                      // 1060*24*4 = 101760 B
    float* partials = (float*)((char*)d_ws + 102400);    // 1280*4    =   5120 B

    build_band<<<(BANDROWS * CBS + 255) / 256, 256, 0, stream>>>(M, band);

    dim3 grid((T_N + CT - 1) / CT,             // 4 t-tiles
              NCHUNK,                          // 10 f-chunks
              B_N);                            // 32 batches -> 1280 blocks
    const int nparts = grid.x * grid.y * grid.z;

    mel_mse_stream<<<grid, NT, 0, stream>>>(mo, tg, band, partials);
    mel_mse_reduce<<<1, 256, 0, stream>>>(partials, nparts, out);
}